// Round 1
// baseline (84.921 us; speedup 1.0000x reference)
//
#include <hip/hip_runtime.h>

#define BB 32
#define CC 1024
#define QQ 128
#define EE 512

typedef unsigned int uint32;
typedef unsigned short u16;
typedef __bf16 bf16x8 __attribute__((ext_vector_type(8)));
typedef float f32x4 __attribute__((ext_vector_type(4)));

// workspace layout (bytes)
#define QM_OFF   (0u)                        // bf16 [B][Q][E]  (question * ws_m)
#define QT_OFF   (4u<<20)                    // bf16 [B][E][Q]  (question transposed)
#define QDOT_OFF (8u<<20)                    // f32  [B][Q]     (question . ws_q)
#define M_OFF    (QDOT_OFF + BB*QQ*4u)       // f32  [B][C]     (row max of sim)
#define MT_OFF   (M_OFF + BB*CC*4u)          // f32  [B][16]    (per-tile max)
#define ST_OFF   (MT_OFF + BB*16*4u)         // f32  [B][16]    (per-tile expsum)
#define PV_OFF   (ST_OFF + BB*16*4u)         // f32  [B][16][E] (per-tile weighted ctx)

__device__ __forceinline__ u16 f2bf(float f){
  uint32 u = __builtin_bit_cast(uint32, f);
  u += 0x7fffu + ((u >> 16) & 1u);           // RNE; inputs are finite
  return (u16)(u >> 16);
}
__device__ __forceinline__ float bf2f(uint32 lo16){
  return __builtin_bit_cast(float, lo16 << 16);
}

// ---------------- prep A: qm = bf16(q * ws_m), qdot = q . ws_q ----------------
__global__ __launch_bounds__(64) void k_prep_row(const float* __restrict__ q,
                                                 const float* __restrict__ ws,
                                                 unsigned char* __restrict__ wsp){
  const int row  = blockIdx.x;               // b*QQ + qi
  const int lane = threadIdx.x;              // 0..63, each lane: 8 elements
  const float4* qr = (const float4*)(q + (size_t)row*EE) + lane*2;
  const float4* wq = (const float4*)(ws) + lane*2;
  const float4* wm = (const float4*)(ws + 2*EE) + lane*2;
  float4 v0 = qr[0], v1 = qr[1];
  float4 a0 = wq[0], a1 = wq[1];
  float4 m0 = wm[0], m1 = wm[1];
  uint4 u;
  u.x = f2bf(v0.x*m0.x) | ((uint32)f2bf(v0.y*m0.y) << 16);
  u.y = f2bf(v0.z*m0.z) | ((uint32)f2bf(v0.w*m0.w) << 16);
  u.z = f2bf(v1.x*m1.x) | ((uint32)f2bf(v1.y*m1.y) << 16);
  u.w = f2bf(v1.z*m1.z) | ((uint32)f2bf(v1.w*m1.w) << 16);
  *(uint4*)(wsp + QM_OFF + (size_t)row*EE*2 + lane*16) = u;
  float dot = v0.x*a0.x + v0.y*a0.y + v0.z*a0.z + v0.w*a0.w
            + v1.x*a1.x + v1.y*a1.y + v1.z*a1.z + v1.w*a1.w;
  #pragma unroll
  for (int off=32; off; off>>=1) dot += __shfl_xor(dot, off);
  if (lane == 0) ((float*)(wsp + QDOT_OFF))[row] = dot;
}

// ---------------- prep B: qT[b][e][q] = bf16(question[b][q][e]) ----------------
__global__ __launch_bounds__(256) void k_prep_t(const float* __restrict__ q,
                                                unsigned char* __restrict__ wsp){
  const int b = blockIdx.x >> 2, ec = blockIdx.x & 3, e0 = ec*128;
  __shared__ u16 tile[128*132];              // [q][e], pad 132 to break conflicts
  const int tid = threadIdx.x;
  #pragma unroll
  for (int i=0;i<16;i++){
    int id = tid + i*256;                    // 0..4095
    int qi = id >> 5;                        // 0..127
    int ex = (id & 31) << 2;                 // 0..124
    float4 v = *(const float4*)(q + (size_t)(b*QQ + qi)*EE + e0 + ex);
    u16* t = &tile[qi*132 + ex];
    t[0]=f2bf(v.x); t[1]=f2bf(v.y); t[2]=f2bf(v.z); t[3]=f2bf(v.w);
  }
  __syncthreads();
  #pragma unroll
  for (int i=0;i<8;i++){
    int id = tid + i*256;                    // 0..2047
    int er = id >> 4;                        // 0..127 (e row)
    int qc = (id & 15) << 3;                 // 0..120 (q chunk of 8)
    uint4 u;
    u.x = (uint32)tile[(qc+0)*132 + er] | ((uint32)tile[(qc+1)*132 + er] << 16);
    u.y = (uint32)tile[(qc+2)*132 + er] | ((uint32)tile[(qc+3)*132 + er] << 16);
    u.z = (uint32)tile[(qc+4)*132 + er] | ((uint32)tile[(qc+5)*132 + er] << 16);
    u.w = (uint32)tile[(qc+6)*132 + er] | ((uint32)tile[(qc+7)*132 + er] << 16);
    *(uint4*)(wsp + QT_OFF + ((size_t)(b*EE + e0 + er)*QQ + qc)*2) = u;
  }
}

// ---------------- main: sim -> softmax -> c2q, row-max m to ws ----------------
// 512 blocks (2/CU), 256 threads (4 waves), 64 ctx rows/block.
// wave w owns rows w*16..w*16+15 x all 128 q cols (M_rep=1, N_rep=8): softmax wave-local.
__global__ __launch_bounds__(256, 2) void k_main(const float* __restrict__ ctx,
                                                 const float* __restrict__ ws,
                                                 unsigned char* __restrict__ wsp,
                                                 float* __restrict__ out){
  __shared__ __align__(16) unsigned char AsB[64*1024]; // ctx tile bf16 [64][512] swizzled; P overlays after GEMM1
  __shared__ float wsc_s[EE];
  __shared__ float cd_s[64];
  __shared__ float qd_s[QQ];
  __shared__ float rden_s[64];

  const int bid = blockIdx.x;
  const int sw  = (bid & 7)*64 + (bid >> 3); // XCD-contiguous swizzle (512 % 8 == 0)
  const int b   = sw >> 4;
  const int c0  = (sw & 15) << 6;
  const int tid = threadIdx.x;
  const int lane = tid & 63;
  const int w    = tid >> 6;
  const int l15  = lane & 15;
  const int l4   = lane >> 4;

  if (tid < QQ) qd_s[tid] = ((const float*)(wsp + QDOT_OFF))[b*QQ + tid];
  wsc_s[tid]       = ws[EE + tid];
  wsc_s[tid + 256] = ws[EE + tid + 256];

  // stage ctx tile -> bf16 LDS, XOR-swizzled (row stride 1024B would be 32-way conflict)
  const float* cbase = ctx + (size_t)(b*CC + c0)*EE;
  #pragma unroll
  for (int i=0;i<16;i++){
    int ch  = tid + i*256;                   // 4096 chunks of 8 elements
    int row = ch >> 6;
    int kc  = ch & 63;
    const float4* p = (const float4*)(cbase + (size_t)row*EE + kc*8);
    float4 x = p[0], y = p[1];
    uint4 u;
    u.x = f2bf(x.x) | ((uint32)f2bf(x.y)<<16);
    u.y = f2bf(x.z) | ((uint32)f2bf(x.w)<<16);
    u.z = f2bf(y.x) | ((uint32)f2bf(y.y)<<16);
    u.w = f2bf(y.z) | ((uint32)f2bf(y.w)<<16);
    *(uint4*)(AsB + row*1024 + ((kc*16) ^ ((row & 7) << 4))) = u;
  }
  __syncthreads();

  // cdot[c] = ctx_row . ws_c (from bf16 LDS copy; error ~bf16 level, fine)
  {
    int row = tid >> 2, part = tid & 3;
    const int swz = (row & 7) << 4;
    float s = 0.f;
    #pragma unroll
    for (int j=0;j<16;j++){
      int k = part*128 + j*8;
      uint4 u = *(const uint4*)(AsB + row*1024 + ((k*2) ^ swz));
      s += bf2f(u.x & 0xffffu)*wsc_s[k+0] + bf2f(u.x >> 16)*wsc_s[k+1]
         + bf2f(u.y & 0xffffu)*wsc_s[k+2] + bf2f(u.y >> 16)*wsc_s[k+3]
         + bf2f(u.z & 0xffffu)*wsc_s[k+4] + bf2f(u.z >> 16)*wsc_s[k+5]
         + bf2f(u.w & 0xffffu)*wsc_s[k+6] + bf2f(u.w >> 16)*wsc_s[k+7];
    }
    s += __shfl_xor(s, 1);
    s += __shfl_xor(s, 2);
    if (part == 0) cd_s[row] = s;
  }

  // GEMM1: sim[64][128] = ctx_bf16 . qm^T  (A from LDS, B-frags direct from L2-hot qm)
  f32x4 acc[8];
  #pragma unroll
  for (int n=0;n<8;n++) acc[n] = (f32x4){0.f,0.f,0.f,0.f};
  {
    const int arow = w*16 + l15;
    const unsigned char* abase = AsB + arow*1024;
    const int aswz = (arow & 7) << 4;
    const uint4* qm4 = (const uint4*)(wsp + QM_OFF);
    const size_t qmbase = ((size_t)(b*QQ + l15)*EE + l4*8) >> 3;
    #pragma unroll 2
    for (int ks=0; ks<16; ks++){
      bf16x8 af = __builtin_bit_cast(bf16x8,
          *(const uint4*)(abase + ((ks*64 + l4*16) ^ aswz)));
      #pragma unroll
      for (int n=0;n<8;n++){
        bf16x8 bq = __builtin_bit_cast(bf16x8, qm4[qmbase + n*1024 + ks*4]);
        acc[n] = __builtin_amdgcn_mfma_f32_16x16x32_bf16(af, bq, acc[n], 0, 0, 0);
      }
    }
  }
  __syncthreads();   // all AsB reads done before P overlays it

  // softmax over q (wave-local rows); write P bf16 into AsB (swizzled), m -> ws
  float* mws = (float*)(wsp + M_OFF) + b*CC + c0;
  #pragma unroll
  for (int r=0;r<4;r++){
    const int row = w*16 + l4*4 + r;         // D-layout: row=(lane>>4)*4+reg
    const float cd = cd_s[row];
    float v[8];
    float mx = -3.0e38f;
    #pragma unroll
    for (int n=0;n<8;n++){
      v[n] = acc[n][r] + cd + qd_s[n*16 + l15];
      mx = fmaxf(mx, v[n]);
    }
    mx = fmaxf(mx, __shfl_xor(mx, 1));
    mx = fmaxf(mx, __shfl_xor(mx, 2));
    mx = fmaxf(mx, __shfl_xor(mx, 4));
    mx = fmaxf(mx, __shfl_xor(mx, 8));
    const int rswz = (row & 7) << 4;
    float sum = 0.f;
    #pragma unroll
    for (int n=0;n<8;n++){
      float p = __expf(v[n] - mx);
      u16 h = f2bf(p);
      sum += bf2f(h);                        // denom over bf16-rounded p (consistent with GEMM2)
      *(u16*)(AsB + row*256 + (((n*16 + l15)*2) ^ rswz)) = h;
    }
    sum += __shfl_xor(sum, 1);
    sum += __shfl_xor(sum, 2);
    sum += __shfl_xor(sum, 4);
    sum += __shfl_xor(sum, 8);
    if (l15 == 0){
      rden_s[row] = 1.f / sum;
      mws[row] = mx;
    }
  }
  __syncthreads();

  // GEMM2: c2q[64][512] = P . question ; wave w owns e-cols w*128..+127 (M_rep=4, N_rep=8)
  f32x4 acc2[4][8];
  #pragma unroll
  for (int m=0;m<4;m++){
    #pragma unroll
    for (int n=0;n<8;n++) acc2[m][n] = (f32x4){0.f,0.f,0.f,0.f};
  }
  {
    const uint4* qt4 = (const uint4*)(wsp + QT_OFF);
    const size_t qtbase = ((size_t)(b*EE + w*128 + l15)*QQ + l4*8) >> 3;
    #pragma unroll
    for (int ks=0; ks<4; ks++){
      bf16x8 a[4];
      #pragma unroll
      for (int m=0;m<4;m++){
        const int row = m*16 + l15;
        a[m] = __builtin_bit_cast(bf16x8,
          *(const uint4*)(AsB + row*256 + ((ks*64 + l4*16) ^ ((row & 7) << 4))));
      }
      #pragma unroll
      for (int n=0;n<8;n++){
        bf16x8 bq = __builtin_bit_cast(bf16x8, qt4[qtbase + n*256 + ks*4]);
        #pragma unroll
        for (int m=0;m<4;m++)
          acc2[m][n] = __builtin_amdgcn_mfma_f32_16x16x32_bf16(a[m], bq, acc2[m][n], 0, 0, 0);
      }
    }
  }
  float* ob = out + (size_t)(b*CC + c0)*EE + w*128;
  #pragma unroll
  for (int m=0;m<4;m++){
    #pragma unroll
    for (int r=0;r<4;r++){
      const int row = m*16 + l4*4 + r;
      const float rd = rden_s[row];
      #pragma unroll
      for (int n=0;n<8;n++){
        ob[(size_t)row*EE + n*16 + l15] = acc2[m][n][r] * rd;
      }
    }
  }
}

// ------------- q2c partials: per (b, 64-row tile) local softmax-weighted ctx sum -------------
__global__ __launch_bounds__(256) void k_q2c_part(const float* __restrict__ ctx,
                                                  unsigned char* __restrict__ wsp){
  const int b = blockIdx.x >> 4, t = blockIdx.x & 15, c0 = t << 6;
  __shared__ float warr[64];
  const int tid = threadIdx.x;
  const float* mws = (const float*)(wsp + M_OFF) + b*CC + c0;
  if (tid < 64){
    float mv = mws[tid];
    float mx = mv;
    #pragma unroll
    for (int off=32; off; off>>=1) mx = fmaxf(mx, __shfl_xor(mx, off));
    float wv = __expf(mv - mx);
    warr[tid] = wv;
    float sv = wv;
    #pragma unroll
    for (int off=32; off; off>>=1) sv += __shfl_xor(sv, off);
    if (tid == 0){
      ((float*)(wsp + MT_OFF))[b*16 + t] = mx;
      ((float*)(wsp + ST_OFF))[b*16 + t] = sv;
    }
  }
  __syncthreads();
  const float* cb = ctx + (size_t)(b*CC + c0)*EE;
  float a0 = 0.f, a1 = 0.f;
  for (int c=0;c<64;c++){
    float wv = warr[c];
    a0 = fmaf(wv, cb[(size_t)c*EE + tid],       a0);
    a1 = fmaf(wv, cb[(size_t)c*EE + tid + 256], a1);
  }
  float* pv = (float*)(wsp + PV_OFF) + (size_t)(b*16 + t)*EE;
  pv[tid]       = a0;
  pv[tid + 256] = a1;
}

// ------------- q2c combine: rescale 16 tile-partials per batch -------------
__global__ __launch_bounds__(256) void k_q2c_fin(unsigned char* __restrict__ wsp,
                                                 float* __restrict__ out){
  const int b = blockIdx.x;
  __shared__ float sc[16];
  const int tid = threadIdx.x;
  if (tid == 0){
    const float* Mt = (const float*)(wsp + MT_OFF) + b*16;
    const float* St = (const float*)(wsp + ST_OFF) + b*16;
    float M = -3.0e38f;
    for (int t=0;t<16;t++) M = fmaxf(M, Mt[t]);
    float den = 0.f;
    float e[16];
    for (int t=0;t<16;t++){ e[t] = __expf(Mt[t]-M); den += e[t]*St[t]; }
    float rd = 1.f/den;
    for (int t=0;t<16;t++) sc[t] = e[t]*rd;
  }
  __syncthreads();
  const float* pv = (const float*)(wsp + PV_OFF) + (size_t)b*16*EE;
  float a0 = 0.f, a1 = 0.f;
  #pragma unroll
  for (int t=0;t<16;t++){
    a0 = fmaf(sc[t], pv[t*EE + tid],       a0);
    a1 = fmaf(sc[t], pv[t*EE + tid + 256], a1);
  }
  size_t base = (size_t)BB*CC*EE + (size_t)b*EE;
  out[base + tid]       = a0;
  out[base + tid + 256] = a1;
}

extern "C" void kernel_launch(void* const* d_in, const int* in_sizes, int n_in,
                              void* d_out, int out_size, void* d_ws, size_t ws_size,
                              hipStream_t stream){
  const float* ctx = (const float*)d_in[0];
  const float* q   = (const float*)d_in[1];
  const float* ws  = (const float*)d_in[2];
  float* out = (float*)d_out;
  unsigned char* wsp = (unsigned char*)d_ws;

  k_prep_row<<<dim3(BB*QQ), dim3(64),  0, stream>>>(q, ws, wsp);
  k_prep_t  <<<dim3(BB*4),  dim3(256), 0, stream>>>(q, wsp);
  k_main    <<<dim3(512),   dim3(256), 0, stream>>>(ctx, ws, wsp, out);
  k_q2c_part<<<dim3(512),   dim3(256), 0, stream>>>(ctx, wsp);
  k_q2c_fin <<<dim3(BB),    dim3(256), 0, stream>>>(wsp, out);
}